// Round 1
// baseline (406.554 us; speedup 1.0000x reference)
//
#include <hip/hip_runtime.h>
#include <hip/hip_bf16.h>
#include <math.h>

typedef __attribute__((ext_vector_type(8))) __bf16 bf16x8;
typedef __attribute__((ext_vector_type(4))) float f32x4;

#define DIM 1024
#define SEQ 2048
#define BATCH 4
#define ROWS (BATCH*SEQ)

__device__ __forceinline__ unsigned short f2bf(float f) {
  unsigned int u = __float_as_uint(f);
  u += 0x7FFF + ((u >> 16) & 1);   // round-to-nearest-even
  return (unsigned short)(u >> 16);
}
__device__ __forceinline__ unsigned short to_bf_bits(float v) { return f2bf(v); }
__device__ __forceinline__ unsigned short to_bf_bits(unsigned short v) { return v; }

__device__ __forceinline__ void gload_lds16(const void* g, void* lds) {
  __builtin_amdgcn_global_load_lds((__attribute__((address_space(1))) void*)g,
                                   (__attribute__((address_space(3))) void*)lds,
                                   16, 0, 0);
}

// ---------- elementwise f32 -> bf16 ----------
__global__ __launch_bounds__(256)
void conv_f32_bf16(const float* __restrict__ src, unsigned short* __restrict__ dst, int n8) {
  int i = blockIdx.x * blockDim.x + threadIdx.x;
  if (i >= n8) return;
  const float4* s = reinterpret_cast<const float4*>(src) + (size_t)i * 2;
  float4 a = s[0], b = s[1];
  union { unsigned short h[8]; uint4 v; } p;
  p.h[0]=f2bf(a.x); p.h[1]=f2bf(a.y); p.h[2]=f2bf(a.z); p.h[3]=f2bf(a.w);
  p.h[4]=f2bf(b.x); p.h[5]=f2bf(b.y); p.h[6]=f2bf(b.z); p.h[7]=f2bf(b.w);
  reinterpret_cast<uint4*>(dst)[i] = p.v;
}

// ---------- transpose + (optional) convert: src[R][C] -> dst[C][R] bf16 ----------
template<typename Tin>
__global__ __launch_bounds__(1024)
void transpose_conv(const Tin* __restrict__ src, int ldsrc,
                    unsigned short* __restrict__ dst, int lddst) {
  __shared__ unsigned short tile[32][33];
  int tx = threadIdx.x, ty = threadIdx.y;
  int r = blockIdx.y * 32 + ty, c = blockIdx.x * 32 + tx;
  tile[ty][tx] = to_bf_bits(src[(size_t)r * ldsrc + c]);
  __syncthreads();
  dst[(size_t)(blockIdx.x * 32 + ty) * lddst + blockIdx.y * 32 + tx] = tile[tx][ty];
}

// ---------- NT GEMM: C[M,N] = A[M,K] * B[N,K]^T, bf16 in, fp32 acc ----------
#define EPI_QKV 0       // + bias, scale cols<DIM by 1/32, bf16 out
#define EPI_F32 1       // plain fp32 out
#define EPI_BF16 2      // plain bf16 out
#define EPI_BIAS_F32 3  // + bias, fp32 out

template<int EPI>
__global__ __launch_bounds__(256)
void gemm_nt(const unsigned short* __restrict__ A, int lda,
             const unsigned short* __restrict__ B, int ldb,
             void* __restrict__ C, int ldc,
             const float* __restrict__ bias, int K) {
  constexpr int BK = 64;
  __shared__ unsigned short As[128 * BK];
  __shared__ unsigned short Bs[128 * BK];
  const int tid = threadIdx.x;
  const int lane = tid & 63, wave = tid >> 6;
  const int wr = wave >> 1, wc = wave & 1;
  const int fr = lane & 15, fk = lane >> 4;
  const int tileM = blockIdx.y * 128, tileN = blockIdx.x * 128;

  f32x4 acc[4][4];
#pragma unroll
  for (int m = 0; m < 4; ++m)
#pragma unroll
    for (int n = 0; n < 4; ++n) acc[m][n] = (f32x4){0.f, 0.f, 0.f, 0.f};

  const int srow = lane >> 3;   // row within a 1KB chunk (8 rows of 128B)
  const int pslot = lane & 7;   // physical 16B slot within the row

  for (int kt = 0; kt < K; kt += BK) {
    __syncthreads();
#pragma unroll
    for (int i = 0; i < 4; ++i) {           // A: chunks wave*4+i (16 chunks total)
      int c = wave * 4 + i;
      int row = c * 8 + srow;
      int ls = pslot ^ (row & 7);           // pre-swizzled global source slot
      gload_lds16(A + (size_t)(tileM + row) * lda + kt + ls * 8, &As[c * 512]);
    }
#pragma unroll
    for (int i = 0; i < 4; ++i) {           // B
      int c = wave * 4 + i;
      int row = c * 8 + srow;
      int ls = pslot ^ (row & 7);
      gload_lds16(B + (size_t)(tileN + row) * ldb + kt + ls * 8, &Bs[c * 512]);
    }
    __syncthreads();
#pragma unroll
    for (int kk = 0; kk < BK; kk += 32) {
      bf16x8 af[4], bg[4];
#pragma unroll
      for (int m = 0; m < 4; ++m) {
        int row = wr * 64 + m * 16 + fr;
        int slot = (kk >> 3) + fk;          // logical 16B slot (8 bf16)
        af[m] = *reinterpret_cast<const bf16x8*>(&As[row * 64 + ((slot ^ (row & 7)) << 3)]);
      }
#pragma unroll
      for (int n = 0; n < 4; ++n) {
        int row = wc * 64 + n * 16 + fr;
        int slot = (kk >> 3) + fk;
        bg[n] = *reinterpret_cast<const bf16x8*>(&Bs[row * 64 + ((slot ^ (row & 7)) << 3)]);
      }
#pragma unroll
      for (int m = 0; m < 4; ++m)
#pragma unroll
        for (int n = 0; n < 4; ++n)
          acc[m][n] = __builtin_amdgcn_mfma_f32_16x16x32_bf16(af[m], bg[n], acc[m][n], 0, 0, 0);
    }
  }

#pragma unroll
  for (int m = 0; m < 4; ++m)
#pragma unroll
    for (int n = 0; n < 4; ++n)
#pragma unroll
      for (int j = 0; j < 4; ++j) {
        int row = tileM + wr * 64 + m * 16 + fk * 4 + j;
        int col = tileN + wc * 64 + n * 16 + fr;
        float v = acc[m][n][j];
        if (EPI == EPI_QKV) {
          v += bias[col];
          if (col < DIM) v *= 0.03125f;   // 1/sqrt(1024), exact pow2
          ((unsigned short*)C)[(size_t)row * ldc + col] = f2bf(v);
        } else if (EPI == EPI_BF16) {
          ((unsigned short*)C)[(size_t)row * ldc + col] = f2bf(v);
        } else if (EPI == EPI_BIAS_F32) {
          ((float*)C)[(size_t)row * ldc + col] = v + bias[col];
        } else {
          ((float*)C)[(size_t)row * ldc + col] = v;
        }
      }
}

// ---------- row softmax: S[row][0..SEQ) fp32 -> P bf16 ----------
__global__ __launch_bounds__(256)
void softmax_kernel(const float* __restrict__ S, unsigned short* __restrict__ P) {
  __shared__ float red[8];
  const int row = blockIdx.x;
  const int tid = threadIdx.x;
  const int lane = tid & 63, wave = tid >> 6;
  const float4* src = reinterpret_cast<const float4*>(S + (size_t)row * SEQ) + tid * 2;
  float4 a = src[0], b = src[1];
  float v[8] = {a.x, a.y, a.z, a.w, b.x, b.y, b.z, b.w};
  float m = v[0];
#pragma unroll
  for (int i = 1; i < 8; ++i) m = fmaxf(m, v[i]);
  for (int o = 32; o; o >>= 1) m = fmaxf(m, __shfl_xor(m, o));
  if (lane == 0) red[wave] = m;
  __syncthreads();
  m = fmaxf(fmaxf(red[0], red[1]), fmaxf(red[2], red[3]));
  float e[8], s = 0.f;
#pragma unroll
  for (int i = 0; i < 8; ++i) { e[i] = expf(v[i] - m); s += e[i]; }
  for (int o = 32; o; o >>= 1) s += __shfl_xor(s, o);
  if (lane == 0) red[4 + wave] = s;
  __syncthreads();
  s = red[4] + red[5] + red[6] + red[7];
  float inv = 1.f / s;
  union { unsigned short h[8]; uint4 u; } p;
#pragma unroll
  for (int i = 0; i < 8; ++i) p.h[i] = f2bf(e[i] * inv);
  reinterpret_cast<uint4*>(P + (size_t)row * SEQ)[tid] = p.u;
}

extern "C" void kernel_launch(void* const* d_in, const int* in_sizes, int n_in,
                              void* d_out, int out_size, void* d_ws, size_t ws_size,
                              hipStream_t stream) {
  const float* X     = (const float*)d_in[0];
  const float* W_in  = (const float*)d_in[1];
  const float* b_in  = (const float*)d_in[2];
  const float* W_out = (const float*)d_in[3];
  const float* b_out = (const float*)d_in[4];
  float* out = (float*)d_out;
  char* ws = (char*)d_ws;

  size_t o = 0;
  auto alloc = [&](size_t bytes) { size_t r = o; o += (bytes + 255) & ~(size_t)255; return r; };
  unsigned short* Xbf   = (unsigned short*)(ws + alloc((size_t)ROWS * DIM * 2));      // aliased as O later
  unsigned short* WinT  = (unsigned short*)(ws + alloc((size_t)3 * DIM * DIM * 2));   // aliased as Vt later
  unsigned short* WoutT = (unsigned short*)(ws + alloc((size_t)DIM * DIM * 2));
  unsigned short* QKV   = (unsigned short*)(ws + alloc((size_t)ROWS * 3 * DIM * 2));
  float*          Sc    = (float*)(ws + alloc((size_t)SEQ * SEQ * 4));
  unsigned short* P     = (unsigned short*)(ws + alloc((size_t)SEQ * SEQ * 2));
  unsigned short* O  = Xbf;   // Xbf dead after QKV GEMM
  unsigned short* Vt = WinT;  // WinT dead after QKV GEMM

  // 1) X -> bf16
  conv_f32_bf16<<<(ROWS * DIM / 8 + 255) / 256, 256, 0, stream>>>(X, Xbf, ROWS * DIM / 8);
  // 2) W_in [DIM][3*DIM] -> WinT [3*DIM][DIM] bf16
  transpose_conv<float><<<dim3(3 * DIM / 32, DIM / 32), dim3(32, 32), 0, stream>>>(W_in, 3 * DIM, WinT, DIM);
  // 3) W_out -> WoutT
  transpose_conv<float><<<dim3(DIM / 32, DIM / 32), dim3(32, 32), 0, stream>>>(W_out, DIM, WoutT, DIM);
  // 4) QKV = Xbf @ WinT^T + b_in (Q scaled by 1/32), bf16 out
  gemm_nt<EPI_QKV><<<dim3(3 * DIM / 128, ROWS / 128), 256, 0, stream>>>(
      Xbf, DIM, WinT, DIM, QKV, 3 * DIM, b_in, DIM);

  for (int b = 0; b < BATCH; ++b) {
    const unsigned short* Qb = QKV + (size_t)b * SEQ * 3 * DIM;
    const unsigned short* Kb = Qb + DIM;
    const unsigned short* Vb = Qb + 2 * DIM;
    unsigned short* Ob = O + (size_t)b * SEQ * DIM;
    // V [SEQ][DIM] (ld 3*DIM) -> Vt [DIM][SEQ]
    transpose_conv<unsigned short><<<dim3(DIM / 32, SEQ / 32), dim3(32, 32), 0, stream>>>(Vb, 3 * DIM, Vt, SEQ);
    // scores = Q @ K^T (already scaled), fp32 out
    gemm_nt<EPI_F32><<<dim3(SEQ / 128, SEQ / 128), 256, 0, stream>>>(
        Qb, 3 * DIM, Kb, 3 * DIM, Sc, SEQ, nullptr, DIM);
    // softmax rows -> P bf16
    softmax_kernel<<<SEQ, 256, 0, stream>>>(Sc, P);
    // O_b = P @ Vt^T, bf16 out
    gemm_nt<EPI_BF16><<<dim3(DIM / 128, SEQ / 128), 256, 0, stream>>>(
        P, SEQ, Vt, SEQ, Ob, DIM, nullptr, SEQ);
  }
  // 5) out = O @ WoutT^T + b_out, fp32
  gemm_nt<EPI_BIAS_F32><<<dim3(DIM / 128, ROWS / 128), 256, 0, stream>>>(
      O, DIM, WoutT, DIM, out, DIM, b_out, DIM);
}

// Round 2
// 243.790 us; speedup vs baseline: 1.6676x; 1.6676x over previous
//
#include <hip/hip_runtime.h>
#include <hip/hip_bf16.h>
#include <math.h>

typedef __attribute__((ext_vector_type(8))) __bf16 bf16x8;
typedef __attribute__((ext_vector_type(4))) float f32x4;

#define DIM 1024
#define SEQ 2048
#define BATCH 4
#define ROWS (BATCH*SEQ)

#define BAR() do { asm volatile("" ::: "memory"); __builtin_amdgcn_s_barrier(); asm volatile("" ::: "memory"); } while(0)
#define WAITV(n) asm volatile("s_waitcnt vmcnt(" #n ")" ::: "memory")

__device__ __forceinline__ unsigned short f2bf(float f) {
  unsigned int u = __float_as_uint(f);
  u += 0x7FFF + ((u >> 16) & 1);   // RNE
  return (unsigned short)(u >> 16);
}
__device__ __forceinline__ unsigned short to_bf_bits(float v) { return f2bf(v); }
__device__ __forceinline__ unsigned short to_bf_bits(unsigned short v) { return v; }

__device__ __forceinline__ void gload_lds16(const void* g, void* lds) {
  __builtin_amdgcn_global_load_lds((__attribute__((address_space(1))) void*)g,
                                   (__attribute__((address_space(3))) void*)lds,
                                   16, 0, 0);
}

// ---------- f32 -> bf16 ----------
__global__ __launch_bounds__(256)
void conv_f32_bf16(const float* __restrict__ src, unsigned short* __restrict__ dst, int n8) {
  int i = blockIdx.x * blockDim.x + threadIdx.x;
  if (i >= n8) return;
  const float4* s = reinterpret_cast<const float4*>(src) + (size_t)i * 2;
  float4 a = s[0], b = s[1];
  union { unsigned short h[8]; uint4 v; } p;
  p.h[0]=f2bf(a.x); p.h[1]=f2bf(a.y); p.h[2]=f2bf(a.z); p.h[3]=f2bf(a.w);
  p.h[4]=f2bf(b.x); p.h[5]=f2bf(b.y); p.h[6]=f2bf(b.z); p.h[7]=f2bf(b.w);
  reinterpret_cast<uint4*>(dst)[i] = p.v;
}

// ---------- transpose+convert: src[R][C] -> dst[C][R] bf16, batched via z ----------
template<typename Tin>
__global__ __launch_bounds__(1024)
void transpose_conv(const Tin* __restrict__ src, int ldsrc, size_t sstride,
                    unsigned short* __restrict__ dst, int lddst, size_t dstride) {
  __shared__ unsigned short tile[32][33];
  const Tin* s = src + (size_t)blockIdx.z * sstride;
  unsigned short* d = dst + (size_t)blockIdx.z * dstride;
  int tx = threadIdx.x, ty = threadIdx.y;
  int r = blockIdx.y * 32 + ty, c = blockIdx.x * 32 + tx;
  tile[ty][tx] = to_bf_bits(s[(size_t)r * ldsrc + c]);
  __syncthreads();
  d[(size_t)(blockIdx.x * 32 + ty) * lddst + blockIdx.y * 32 + tx] = tile[tx][ty];
}

// ---------- phase-pipelined NT GEMM: C[M,N] = A[M,K]*B[N,K]^T ----------
// BM=256, BN in {256,128}, 8 waves (2Mx4N), per-wave 128 x (BN/2).
// LDS: ring of 4 k-slices (k=32 each): A 256x32, B BNx32, XOR-swizzled 16B slots.
// Staging runs 2 slices ahead; counted vmcnt (8 / 6) keeps loads in flight
// across barriers (T3+T4); setprio around MFMA cluster (T5).
#define EPI_QKV 0
#define EPI_F32 1
#define EPI_BF16 2
#define EPI_BIAS_F32 3

template<int BN, int EPI>
__global__ __launch_bounds__(512, 2)
void gemm8(const unsigned short* __restrict__ A, int lda, size_t sA,
           const unsigned short* __restrict__ B, int ldb, size_t sB,
           void* __restrict__ C, int ldc, size_t sC,
           const float* __restrict__ bias, int K) {
  constexpr int NREP = BN / 64;     // B frags per wave: 4 or 2
  constexpr int NW = 16 * NREP;     // per-wave col width: 64 or 32
  constexpr int BCH = BN / 16;      // B chunks (1KB) per slice: 16 or 8
  __shared__ unsigned short As[4 * 256 * 32];
  __shared__ unsigned short Bs[4 * BN * 32];

  const int tid = threadIdx.x;
  const int lane = tid & 63, wave = tid >> 6;
  const int wm = wave >> 2, wn = wave & 3;
  const int fr = lane & 15, fk = lane >> 4;
  const int tileM = blockIdx.y * 256, tileN = blockIdx.x * BN;
  const unsigned short* Ab = A + (size_t)blockIdx.z * sA;
  const unsigned short* Bb = B + (size_t)blockIdx.z * sB;
  const int srow = lane >> 2;       // row within 1KB chunk (16 rows of 64B)
  const int sslot = lane & 3;       // physical 16B slot within row

  auto stage = [&](int sl, int k0) {
#pragma unroll
    for (int q = 0; q < 2; ++q) {   // A: 16 chunks, wave does {wave, wave+8}
      int c = wave + q * 8;
      int r = c * 16 + srow;
      int g = sslot ^ ((r >> 1) & 3);         // pre-swizzled global source slot
      gload_lds16(Ab + (size_t)(tileM + r) * lda + k0 + g * 8,
                  &As[sl * (256 * 32) + c * 512]);
    }
#pragma unroll
    for (int q = 0; q < BCH / 8; ++q) {
      int c = wave + q * 8;
      int r = c * 16 + srow;
      int g = sslot ^ ((r >> 1) & 3);
      gload_lds16(Bb + (size_t)(tileN + r) * ldb + k0 + g * 8,
                  &Bs[sl * (BN * 32) + c * 512]);
    }
  };

  f32x4 acc[8][NREP];
#pragma unroll
  for (int m = 0; m < 8; ++m)
#pragma unroll
    for (int n = 0; n < NREP; ++n) acc[m][n] = (f32x4){0.f, 0.f, 0.f, 0.f};

  const int NS = K >> 5;            // k-slices of 32
  stage(0, 0);
  stage(1, 32);

  for (int p = 0; p < NS; ++p) {
    if (p + 2 < NS) {
      stage((p + 2) & 3, (p + 2) << 5);
      if (BN == 256) { WAITV(8); } else { WAITV(6); }   // retire slice p only
    } else if (p + 2 == NS) {
      if (BN == 256) { WAITV(4); } else { WAITV(3); }
    } else {
      WAITV(0);
    }
    BAR();
    const unsigned short* Asl = &As[(p & 3) * (256 * 32)];
    const unsigned short* Bsl = &Bs[(p & 3) * (BN * 32)];
    bf16x8 af[8], bg[NREP];
#pragma unroll
    for (int m = 0; m < 8; ++m) {
      int r = wm * 128 + m * 16 + fr;
      af[m] = *reinterpret_cast<const bf16x8*>(&Asl[r * 32 + ((fk ^ ((r >> 1) & 3)) * 8)]);
    }
#pragma unroll
    for (int n = 0; n < NREP; ++n) {
      int r = wn * NW + n * 16 + fr;
      bg[n] = *reinterpret_cast<const bf16x8*>(&Bsl[r * 32 + ((fk ^ ((r >> 1) & 3)) * 8)]);
    }
    __builtin_amdgcn_s_setprio(1);
#pragma unroll
    for (int m = 0; m < 8; ++m)
#pragma unroll
      for (int n = 0; n < NREP; ++n)
        acc[m][n] = __builtin_amdgcn_mfma_f32_16x16x32_bf16(af[m], bg[n], acc[m][n], 0, 0, 0);
    __builtin_amdgcn_s_setprio(0);
  }

#pragma unroll
  for (int m = 0; m < 8; ++m)
#pragma unroll
    for (int n = 0; n < NREP; ++n)
#pragma unroll
      for (int j = 0; j < 4; ++j) {
        int row = tileM + wm * 128 + m * 16 + fk * 4 + j;
        int col = tileN + wn * NW + n * 16 + fr;
        float v = acc[m][n][j];
        if (EPI == EPI_QKV) {
          v += bias[col];
          if (col < DIM) v *= 0.03125f;   // 1/sqrt(1024)
          ((unsigned short*)C + (size_t)blockIdx.z * sC)[(size_t)row * ldc + col] = f2bf(v);
        } else if (EPI == EPI_BF16) {
          ((unsigned short*)C + (size_t)blockIdx.z * sC)[(size_t)row * ldc + col] = f2bf(v);
        } else if (EPI == EPI_BIAS_F32) {
          ((float*)C + (size_t)blockIdx.z * sC)[(size_t)row * ldc + col] = v + bias[col];
        } else {
          ((float*)C + (size_t)blockIdx.z * sC)[(size_t)row * ldc + col] = v;
        }
      }
}

// ---------- row softmax, in-place: fp32 row -> bf16 P at row start ----------
__global__ __launch_bounds__(256)
void softmax_kernel(float* __restrict__ S, size_t zstride) {
  __shared__ float red[8];
  float* row = S + (size_t)blockIdx.y * zstride + (size_t)blockIdx.x * SEQ;
  const int tid = threadIdx.x;
  const int lane = tid & 63, wave = tid >> 6;
  const float4* src = reinterpret_cast<const float4*>(row) + tid * 2;
  float4 a = src[0], b = src[1];
  float v[8] = {a.x, a.y, a.z, a.w, b.x, b.y, b.z, b.w};
  float m = v[0];
#pragma unroll
  for (int i = 1; i < 8; ++i) m = fmaxf(m, v[i]);
  for (int o = 32; o; o >>= 1) m = fmaxf(m, __shfl_xor(m, o));
  if (lane == 0) red[wave] = m;
  __syncthreads();
  m = fmaxf(fmaxf(red[0], red[1]), fmaxf(red[2], red[3]));
  float e[8], s = 0.f;
#pragma unroll
  for (int i = 0; i < 8; ++i) { e[i] = expf(v[i] - m); s += e[i]; }
  for (int o = 32; o; o >>= 1) s += __shfl_xor(s, o);
  if (lane == 0) red[4 + wave] = s;
  __syncthreads();
  s = red[4] + red[5] + red[6] + red[7];
  float inv = 1.f / s;
  union { unsigned short h[8]; uint4 u; } p;
#pragma unroll
  for (int i = 0; i < 8; ++i) p.h[i] = f2bf(e[i] * inv);
  reinterpret_cast<uint4*>(row)[tid] = p.u;   // safe: all reads precede barriers above
}

extern "C" void kernel_launch(void* const* d_in, const int* in_sizes, int n_in,
                              void* d_out, int out_size, void* d_ws, size_t ws_size,
                              hipStream_t stream) {
  const float* X     = (const float*)d_in[0];
  const float* W_in  = (const float*)d_in[1];
  const float* b_in  = (const float*)d_in[2];
  const float* W_out = (const float*)d_in[3];
  const float* b_out = (const float*)d_in[4];
  float* out = (float*)d_out;
  char* ws = (char*)d_ws;

  // fixed allocations
  size_t o = 0;
  auto alloc = [&](size_t bytes) { size_t r = o; o += (bytes + 255) & ~(size_t)255; return r; };
  unsigned short* Xbf   = (unsigned short*)(ws + alloc((size_t)ROWS * DIM * 2));     // aliased as O later
  unsigned short* WinT  = (unsigned short*)(ws + alloc((size_t)3 * DIM * DIM * 2));
  unsigned short* WoutT = (unsigned short*)(ws + alloc((size_t)DIM * DIM * 2));
  unsigned short* QKV   = (unsigned short*)(ws + alloc((size_t)ROWS * 3 * DIM * 2));
  size_t fixed = o;
  size_t per_batch = (((size_t)SEQ * SEQ * 4 + 255) & ~(size_t)255) +
                     (((size_t)DIM * SEQ * 2 + 255) & ~(size_t)255);
  int G = (ws_size >= fixed + 4 * per_batch) ? BATCH : 1;   // deterministic given ws_size
  float*          Sc = (float*)(ws + alloc((size_t)G * SEQ * SEQ * 4));  // P written in place (bf16)
  unsigned short* Vt = (unsigned short*)(ws + alloc((size_t)G * DIM * SEQ * 2));
  unsigned short* O  = Xbf;   // Xbf dead after QKV GEMM

  conv_f32_bf16<<<(ROWS * DIM / 8 + 255) / 256, 256, 0, stream>>>(X, Xbf, ROWS * DIM / 8);
  transpose_conv<float><<<dim3(3 * DIM / 32, DIM / 32, 1), dim3(32, 32), 0, stream>>>(
      W_in, 3 * DIM, 0, WinT, DIM, 0);
  transpose_conv<float><<<dim3(DIM / 32, DIM / 32, 1), dim3(32, 32), 0, stream>>>(
      W_out, DIM, 0, WoutT, DIM, 0);
  // QKV = Xbf @ WinT^T + b_in (Q cols pre-scaled), bf16
  gemm8<256, EPI_QKV><<<dim3(3 * DIM / 256, ROWS / 256, 1), 512, 0, stream>>>(
      Xbf, DIM, 0, WinT, DIM, 0, QKV, 3 * DIM, 0, b_in, DIM);

  for (int b0 = 0; b0 < BATCH; b0 += G) {
    const unsigned short* Qb = QKV + (size_t)b0 * SEQ * 3 * DIM;
    const unsigned short* Kb = Qb + DIM;
    const unsigned short* Vb = Qb + 2 * DIM;
    // V -> Vt [DIM][SEQ]
    transpose_conv<unsigned short><<<dim3(DIM / 32, SEQ / 32, G), dim3(32, 32), 0, stream>>>(
        Vb, 3 * DIM, (size_t)SEQ * 3 * DIM, Vt, SEQ, (size_t)DIM * SEQ);
    // scores = Q @ K^T (fp32)
    gemm8<256, EPI_F32><<<dim3(SEQ / 256, SEQ / 256, G), 512, 0, stream>>>(
        Qb, 3 * DIM, (size_t)SEQ * 3 * DIM, Kb, 3 * DIM, (size_t)SEQ * 3 * DIM,
        Sc, SEQ, (size_t)SEQ * SEQ, nullptr, DIM);
    // softmax rows, P bf16 in place over Sc rows
    softmax_kernel<<<dim3(SEQ, G), 256, 0, stream>>>(Sc, (size_t)SEQ * SEQ);
    // O_b = P @ Vt^T  (P: lda = 2*SEQ shorts, bf16 rows at fp32-row starts)
    gemm8<128, EPI_BF16><<<dim3(DIM / 128, SEQ / 256, G), 512, 0, stream>>>(
        (const unsigned short*)Sc, 2 * SEQ, (size_t)2 * SEQ * SEQ,
        Vt, SEQ, (size_t)DIM * SEQ,
        O + (size_t)b0 * SEQ * DIM, DIM, (size_t)SEQ * DIM, nullptr, SEQ);
  }
  // out = O @ WoutT^T + b_out (fp32)
  gemm8<128, EPI_BIAS_F32><<<dim3(DIM / 128, ROWS / 256, 1), 512, 0, stream>>>(
      O, DIM, 0, WoutT, DIM, 0, out, DIM, 0, b_out, DIM);
}